// Round 11
// baseline (668.396 us; speedup 1.0000x reference)
//
#include <hip/hip_runtime.h>
#include <hip/hip_bf16.h>

#define BB 16
#define XY 64
#define CC 256
#define PR 66   // padded rows/cols (64 + halo)

typedef __attribute__((ext_vector_type(8)))  short short8;
typedef __attribute__((ext_vector_type(16))) float f32x16;
typedef __hip_bfloat16 bf16;

__device__ __forceinline__ void glds16(const void* g, void* l) {
  __builtin_amdgcn_global_load_lds(
      (const __attribute__((address_space(1))) void*)g,
      (__attribute__((address_space(3))) void*)l, 16, 0, 0);
}

// ---------------- Kernel 1: conv1 + BN1 + ReLU -> act[b][prow 66][kg 32][wp 66][8] bf16
__global__ __launch_bounds__(256) void k_conv1(
    const float* __restrict__ in,      // (B,64,64)
    const float* __restrict__ w1,      // (C,1,3,3)
    const float* __restrict__ g, const float* __restrict__ bbias,
    const float* __restrict__ m, const float* __restrict__ v,
    bf16* __restrict__ act)
{
  int blk = blockIdx.x;
  int b = blk / PR, prow = blk % PR;
  short8* base = (short8*)(act + (size_t)(b * PR + prow) * 32 * PR * 8);
  int tid = threadIdx.x;
  short8 z8 = {0, 0, 0, 0, 0, 0, 0, 0};
  if (prow == 0 || prow == PR - 1) {
    for (int i = tid; i < 32 * PR; i += 256) base[i] = z8;
    return;
  }
  __shared__ float inrow[3][PR];
  int h = prow - 1;
  for (int t = tid; t < 3 * PR; t += 256) {
    int r = t / PR, x = t % PR;
    int hr = h - 1 + r, wr = x - 1;
    inrow[r][x] = (hr >= 0 && hr < XY && wr >= 0 && wr < XY)
                      ? in[(b * XY + hr) * XY + wr] : 0.f;
  }
  __syncthreads();
  int cg = tid >> 3, w8 = tid & 7;
  float wr_[8][9], sc[8], tc[8];
#pragma unroll
  for (int u = 0; u < 8; ++u) {
    int c = cg * 8 + u;
#pragma unroll
    for (int t = 0; t < 9; ++t) wr_[u][t] = w1[c * 9 + t];
    float s = g[c] * rsqrtf(v[c] + 1e-5f);
    sc[u] = s; tc[u] = bbias[c] - m[c] * s;
  }
#pragma unroll
  for (int k = 0; k < 9; ++k) {
    int wp = w8 + 8 * k;
    if (wp < PR) {
      short8 outv = z8;
      if (wp != 0 && wp != PR - 1) {
        float o[8];
#pragma unroll
        for (int u = 0; u < 8; ++u) o[u] = 0.f;
#pragma unroll
        for (int dy = 0; dy < 3; ++dy) {
          float i0 = inrow[dy][wp - 1], i1 = inrow[dy][wp], i2 = inrow[dy][wp + 1];
#pragma unroll
          for (int u = 0; u < 8; ++u)
            o[u] += i0 * wr_[u][dy * 3] + i1 * wr_[u][dy * 3 + 1] + i2 * wr_[u][dy * 3 + 2];
        }
#pragma unroll
        for (int u = 0; u < 8; ++u) {
          bf16 hb = __float2bfloat16(fmaxf(fmaf(o[u], sc[u], tc[u]), 0.f));
          outv[u] = *(short*)&hb;
        }
      }
      base[cg * PR + wp] = outv;
    }
  }
}

// ---------------- Kernel 2: w2 -> Wb[(tap*4+cp)][kg 8][co 256][8] bf16, BN2-scaled
// ci = cp*64 + kg*8 + j; each (tap,cp) block = 32 KB contiguous [kg][co][8].
__global__ __launch_bounds__(256) void k_wb(
    const float* __restrict__ w2,      // (co, ci, 3, 3)
    const float* __restrict__ g, const float* __restrict__ v,
    bf16* __restrict__ Wb)
{
  int e = blockIdx.x * 256 + threadIdx.x;   // < 589824
  int j   = e & 7;
  int co  = (e >> 3) & 255;
  int kg  = (e >> 11) & 7;
  int cp  = (e >> 14) & 3;
  int tap = e >> 16;
  int ci = cp * 64 + kg * 8 + j;
  float s = g[co] * rsqrtf(v[co] + 1e-5f);
  Wb[e] = __float2bfloat16(w2[((size_t)co * CC + ci) * 9 + tap] * s);
}

// ---------------- Kernel 3: conv2, m201-style 2-phase/iter 8-wave pipeline -----
// BM=256 (4 out rows), BN=256, 512 thr = 8 waves (wm=wid>>2 rows, wn=wid&3 co).
// Wave tile 128 wp x 64 co = 4x2 tiles of 32x32 (acc 128 AGPR). 36 iters
// (cp x tap), K=64. W 32KB blocks TRIPLE-buffered, staged 2 iters ahead in
// 2-glds slivers per phase; uniform vmcnt(4) never drains in the loop.
// A (6 rows x 8 kg x 66) single-buffered, re-staged at cp boundaries.
__global__ __launch_bounds__(512, 2) void k_conv2(
    const bf16* __restrict__ act,      // (B,66,32,66,8)
    const bf16* __restrict__ Wb,       // (36,8,256,8)
    const float* __restrict__ in,      // (B,64,64) residual
    const float* __restrict__ g2, const float* __restrict__ b2,
    const float* __restrict__ m2, const float* __restrict__ v2,
    float* __restrict__ out)           // (B,4096,256)
{
  __shared__ alignas(16) bf16 Asm[3168 * 8];     // 50688 B  chunk (prow*8+kg)*66+wp
  __shared__ alignas(16) bf16 Wsm[3][2048 * 8];  // 98304 B  chunk kg*256+co
  __shared__ float inrow[4][64];

  int gg = blockIdx.x;                  // 256 blocks; XCD swizzle (256%8==0)
  int blk = (gg & 7) * 32 + (gg >> 3);
  int b = blk >> 4, h0 = (blk & 15) << 2;

  int tid = threadIdx.x;
  int lane = tid & 63, wid = tid >> 6;
  int wm = wid >> 2, wn = wid & 3;
  int l31 = lane & 31, lh = lane >> 5;

  f32x16 acc[4][2];                     // [mt][nt]
#pragma unroll
  for (int i = 0; i < 4; ++i)
#pragma unroll
    for (int j = 0; j < 2; ++j)
#pragma unroll
      for (int e = 0; e < 16; ++e) acc[i][j][e] = 0.f;

  if (tid < 256) inrow[tid >> 6][tid & 63] = in[(b * XY + h0 + (tid >> 6)) * XY + (tid & 63)];
  __syncthreads();   // drains everything; manual counting starts clean

  // A stage: 3168 chunks (6 padded rows h0..h0+5, 8 kg, 66 wp); 7 glds/wave,
  // overlapping partition (benign double-writes), uniform count per wave.
  auto stageA = [&](int cp) {
    int base_g = ((b * PR + h0) * 32 + cp * 8) * 66;   // global chunk base
#pragma unroll
    for (int k = 0; k < 7; ++k) {
      int sb = wid * 396 + k * 64;
      if (sb > 3104) sb = 3104;
      int s = sb + lane;
      int prow = s / 528;                               // local padded row
      int gsrc = base_g + s + prow * 1584;              // global kg-stride 32 vs 8
      glds16((const char*)act + (size_t)gsrc * 16, (char*)Asm + (size_t)sb * 16);
    }
  };
  // half a wave-share of one 32KB W block: 2 glds (1 KB each); per-lane src!
  auto stageW2 = [&](int wblk, int sbuf, int half) {
    const char* src = (const char*)Wb + (size_t)wblk * 32768 + wid * 4096 + half * 2048;
    char* dst = (char*)&Wsm[0][0] + (size_t)sbuf * 32768 + wid * 4096 + half * 2048;
    glds16(src + lane * 16, dst);
    glds16(src + 1024 + lane * 16, dst + 1024);
  };

  // ---- prologue: A(cp0) [7], W(it0)->buf0 [4], W(it1)->buf1 [4] ----
  stageA(0);
  stageW2(0, 0, 0); stageW2(0, 0, 1);     // it0 = (tap0,cp0), wblk 0
  stageW2(4, 1, 0); stageW2(4, 1, 1);     // it1 = (tap1,cp0), wblk 4
  asm volatile("s_waitcnt vmcnt(4)" ::: "memory");   // A + W0 done; W1 in flight
  __builtin_amdgcn_s_barrier();

  int buf = 0;
#pragma unroll 1
  for (int cp = 0; cp < 4; ++cp) {
#pragma unroll 1
    for (int tap = 0; tap < 9; ++tap) {
      int t = cp * 9 + tap;
      int dy = tap / 3, dx = tap - dy * 3;
      int sbuf = buf + 2; if (sbuf >= 3) sbuf -= 3;
      int tap2 = tap + 2, cp2 = cp;
      if (tap2 >= 9) { tap2 -= 9; ++cp2; }
      int wblk2 = tap2 * 4 + cp2;
      bool doW = (t <= 33);

      const bf16* wb_ = (const bf16*)((const char*)&Wsm[0][0] + (size_t)buf * 32768);
      int a00 = (2 * wm + dy) * 528 + lh * 66 + l31 + dx;   // chunk, mt=0,s=0
      int b00 = lh * 256 + wn * 64 + l31;                   // chunk, nt=0,s=0

      if (tap < 8) {
        // ======== phase 1: s = 0,1 ========
        short8 aP[2][4], wP[2][2];
#pragma unroll
        for (int s = 0; s < 2; ++s)
#pragma unroll
          for (int mt = 0; mt < 4; ++mt)
            aP[s][mt] = *(const short8*)(Asm +
                (size_t)(a00 + (mt >> 1) * 528 + (mt & 1) * 32 + s * 132) * 8);
#pragma unroll
        for (int s = 0; s < 2; ++s)
#pragma unroll
          for (int nt = 0; nt < 2; ++nt)
            wP[s][nt] = *(const short8*)(wb_ + (size_t)(b00 + nt * 32 + s * 512) * 8);
        if (doW) stageW2(wblk2, sbuf, 0);
        __builtin_amdgcn_s_barrier();
        __builtin_amdgcn_s_setprio(1);
#pragma unroll
        for (int s = 0; s < 2; ++s)
#pragma unroll
          for (int mt = 0; mt < 4; ++mt)
#pragma unroll
            for (int nt = 0; nt < 2; ++nt)
              acc[mt][nt] = __builtin_amdgcn_mfma_f32_32x32x16_bf16(
                  aP[s][mt], wP[s][nt], acc[mt][nt], 0, 0, 0);
        __builtin_amdgcn_s_setprio(0);
        // ======== phase 2: s = 2,3 ========
        short8 aQ[2][4], wQ[2][2];
#pragma unroll
        for (int s = 0; s < 2; ++s)
#pragma unroll
          for (int mt = 0; mt < 4; ++mt)
            aQ[s][mt] = *(const short8*)(Asm +
                (size_t)(a00 + (mt >> 1) * 528 + (mt & 1) * 32 + (s + 2) * 132) * 8);
#pragma unroll
        for (int s = 0; s < 2; ++s)
#pragma unroll
          for (int nt = 0; nt < 2; ++nt)
            wQ[s][nt] = *(const short8*)(wb_ + (size_t)(b00 + nt * 32 + (s + 2) * 512) * 8);
        if (doW) stageW2(wblk2, sbuf, 1);
        __builtin_amdgcn_s_barrier();
        __builtin_amdgcn_s_setprio(1);
#pragma unroll
        for (int s = 0; s < 2; ++s)
#pragma unroll
          for (int mt = 0; mt < 4; ++mt)
#pragma unroll
            for (int nt = 0; nt < 2; ++nt)
              acc[mt][nt] = __builtin_amdgcn_mfma_f32_32x32x16_bf16(
                  aQ[s][mt], wQ[s][nt], acc[mt][nt], 0, 0, 0);
        __builtin_amdgcn_s_setprio(0);
        if (t == 34) asm volatile("s_waitcnt vmcnt(0)" ::: "memory");
        else         asm volatile("s_waitcnt vmcnt(4)" ::: "memory");
        __builtin_amdgcn_s_barrier();
      } else {
        // ======== boundary iter (tap 8): all reads, all MFMA, then restage ====
        short8 aB[4][4], wB[4][2];
#pragma unroll
        for (int s = 0; s < 4; ++s)
#pragma unroll
          for (int mt = 0; mt < 4; ++mt)
            aB[s][mt] = *(const short8*)(Asm +
                (size_t)(a00 + (mt >> 1) * 528 + (mt & 1) * 32 + s * 132) * 8);
#pragma unroll
        for (int s = 0; s < 4; ++s)
#pragma unroll
          for (int nt = 0; nt < 2; ++nt)
            wB[s][nt] = *(const short8*)(wb_ + (size_t)(b00 + nt * 32 + s * 512) * 8);
        __builtin_amdgcn_s_barrier();
        __builtin_amdgcn_s_setprio(1);
#pragma unroll
        for (int s = 0; s < 4; ++s)
#pragma unroll
          for (int mt = 0; mt < 4; ++mt)
#pragma unroll
            for (int nt = 0; nt < 2; ++nt)
              acc[mt][nt] = __builtin_amdgcn_mfma_f32_32x32x16_bf16(
                  aB[s][mt], wB[s][nt], acc[mt][nt], 0, 0, 0);
        __builtin_amdgcn_s_setprio(0);
        __builtin_amdgcn_s_barrier();   // all waves' A-reads consumed before restage
        if (cp < 3) stageA(cp + 1);     // 7 glds (counted ahead of this iter's W)
        if (doW) { stageW2(wblk2, sbuf, 0); stageW2(wblk2, sbuf, 1); }
        asm volatile("s_waitcnt vmcnt(4)" ::: "memory");  // retires prev-W4 + A7
        __builtin_amdgcn_s_barrier();
      }
      buf = (buf == 2) ? 0 : buf + 1;
    }
  }

  // ---- epilogue: +bias2, ReLU, +input, ReLU ----
  // C/D (32x32): col = l31 (co), row = (e&3) + 8*(e>>2) + 4*lh  [m74/m101]
  float t2[2];
#pragma unroll
  for (int nt = 0; nt < 2; ++nt) {
    int co = wn * 64 + nt * 32 + l31;
    float s2 = g2[co] * rsqrtf(v2[co] + 1e-5f);
    t2[nt] = b2[co] - m2[co] * s2;
  }
#pragma unroll
  for (int mt = 0; mt < 4; ++mt) {
    int rloc = 2 * wm + (mt >> 1);
    float* obr = out + ((size_t)(b * XY + h0 + rloc)) * XY * CC;
#pragma unroll
    for (int e = 0; e < 16; ++e) {
      int wp = (mt & 1) * 32 + (e & 3) + 8 * (e >> 2) + 4 * lh;
      float iv = inrow[rloc][wp];
      float* ob = obr + (size_t)wp * CC + wn * 64 + l31;
#pragma unroll
      for (int nt = 0; nt < 2; ++nt) {
        float val = fmaxf(acc[mt][nt][e] + t2[nt], 0.f);
        ob[nt * 32] = fmaxf(iv + val, 0.f);
      }
    }
  }
}

extern "C" void kernel_launch(void* const* d_in, const int* in_sizes, int n_in,
                              void* d_out, int out_size, void* d_ws, size_t ws_size,
                              hipStream_t stream) {
  const float* in_   = (const float*)d_in[0];   // (16,64,64)
  const float* w1    = (const float*)d_in[3];   // (256,1,3,3)
  const float* w2    = (const float*)d_in[4];   // (256,256,3,3)
  const float* bn1_g = (const float*)d_in[5];
  const float* bn1_b = (const float*)d_in[6];
  const float* bn1_m = (const float*)d_in[7];
  const float* bn1_v = (const float*)d_in[8];
  const float* bn2_g = (const float*)d_in[9];
  const float* bn2_b = (const float*)d_in[10];
  const float* bn2_m = (const float*)d_in[11];
  const float* bn2_v = (const float*)d_in[12];
  float* out = (float*)d_out;

  bf16* act = (bf16*)d_ws;                         // (16,66,32,66,8) bf16 = 35.7 MB
  bf16* Wb  = act + (size_t)BB * PR * 32 * PR * 8; // (36,8,256,8) bf16 = 1.18 MB

  k_conv1<<<BB * PR, 256, 0, stream>>>(in_, w1, bn1_g, bn1_b, bn1_m, bn1_v, act);
  k_wb<<<2304, 256, 0, stream>>>(w2, bn2_g, bn2_v, Wb);
  k_conv2<<<256, 512, 0, stream>>>(act, Wb, in_, bn2_g, bn2_b, bn2_m, bn2_v, out);
}